// Round 6
// baseline (589.751 us; speedup 1.0000x reference)
//
#include <hip/hip_runtime.h>
#include <stdint.h>

// CSENet: per-pixel argmin over 27554 vertex embeddings (16-dim, fp32).
// (A) bf16 MFMA approx scores s~ = c2 - 2 x.w (c2 folded into K slots),
//     min-only reduce -> per-(pixel,chunk) min table.
// (B1) per-pixel threshold (provable bf16 margin), scatter candidates into
//      per-chunk buckets.
// (B2) one wave per candidate (pixel,chunk): exact fp32 rescan of the chunk
//      from LDS (80B row stride -> conflict-free), packed u64 atomicMin.

#define DIMS   16
#define HW     12544
#define P_TOT  50176
#define V_TOT  27554
#define FEAT_N 802816

#define CV     512
#define NCH    54
#define VPAD   (NCH*CV)
#define PIXW   128
#define TPW    8
#define B2BX   32

// fallback (round-1) path
#define NV     64
#define VC     431
#define PPT    4

typedef __attribute__((ext_vector_type(8))) short bf16x8;
typedef __attribute__((ext_vector_type(4))) float f32x4;

// ---- big-ws layout (bytes) ----
#define OFF_KEYS  0ul
#define OFF_N2MAX 401408ul
#define OFF_C2    401664ul
#define OFF_XN    512000ul
#define OFF_X2T   712704ul
#define OFF_XB    3923968ul
#define OFF_WB    7135232ul
#define OFF_CM    8904704ul
#define OFF_CNT   19742720ul
#define OFF_BKT   19742976ul
#define WS_BIG    30580992ul
// ---- mid-ws layout (round-2, proven) ----
#define MOFF_KEYS  0ul
#define MOFF_N2MAX 401408ul
#define MOFF_C2    405504ul
#define MOFF_XN    516096ul
#define MOFF_XB    716800ul
#define MOFF_WB    3928064ul
#define MOFF_CM    5697536ul
#define WS_MID     16535552ul

__device__ __forceinline__ unsigned short rne_bf16(float f) {
    unsigned u = __float_as_uint(f);
    return (unsigned short)((u + 0x7FFFu + ((u >> 16) & 1u)) >> 16);
}
__device__ __forceinline__ float bf2f(unsigned short h) {
    return __uint_as_float(((unsigned)h) << 16);
}
__device__ __forceinline__ unsigned sortable(float s) {
    unsigned u = __float_as_uint(s);
    return (u & 0x80000000u) ? ~u : (u | 0x80000000u);
}

// ---------------- prep: vertices -> bf16 A-fragments + c2 + max|w~|^2 -----
__global__ void prep_v(const float* __restrict__ ve, short* __restrict__ wb,
                       float* __restrict__ c2buf, unsigned* __restrict__ n2max)
{
    int v = blockIdx.x * 256 + threadIdx.x;
    if (v >= VPAD) return;
    int c = v / CV, vl = v % CV;
    bf16x8 r0, r1, r2, r3;
#pragma unroll
    for (int k = 0; k < 8; ++k) { r2[k] = 0; r3[k] = 0; }
    if (v < V_TOT) {
        const float4* w4 = (const float4*)(ve + (size_t)v * DIMS);
        float w[16];
        *(float4*)&w[0] = w4[0]; *(float4*)&w[4]  = w4[1];
        *(float4*)&w[8] = w4[2]; *(float4*)&w[12] = w4[3];
        float c2 = 0.f;
#pragma unroll
        for (int k = 0; k < 16; ++k) c2 = fmaf(w[k], w[k], c2);
        c2buf[v] = c2;
        float n2 = 0.f;
#pragma unroll
        for (int k = 0; k < 16; ++k) {
            unsigned short h = rne_bf16(-2.f * w[k]);
            if (k < 8) r0[k] = (short)h; else r1[k - 8] = (short)h;
            float f = bf2f(h);
            n2 = fmaf(f, f, n2);
        }
        atomicMax(n2max, __float_as_uint(n2));
        unsigned short hi = rne_bf16(c2);
        unsigned short lo = rne_bf16(c2 - bf2f(hi));
        r2[0] = (short)hi; r2[1] = (short)lo;
    } else {
#pragma unroll
        for (int k = 0; k < 8; ++k) { r0[k] = 0; r1[k] = 0; }
        r2[0] = (short)rne_bf16(30000.f);   // padding: huge score, never wins
    }
    *(bf16x8*)(wb + (((size_t)c * 4 + 0) * CV + vl) * 8) = r0;
    *(bf16x8*)(wb + (((size_t)c * 4 + 1) * CV + vl) * 8) = r1;
    *(bf16x8*)(wb + (((size_t)c * 4 + 2) * CV + vl) * 8) = r2;
    *(bf16x8*)(wb + (((size_t)c * 4 + 3) * CV + vl) * 8) = r3;
}

// ------- prep: pixels -> bf16 B-fragments + |x~| (+ optional fp32 -2x) -----
__global__ void prep_x(const float* __restrict__ feats, short* __restrict__ xb,
                       float* __restrict__ xn, float* __restrict__ x2T)
{
    int p = blockIdx.x * 256 + threadIdx.x;
    int b = p / HW, hw = p - b * HW;
    const float* f = feats + (size_t)b * DIMS * HW + hw;
    bf16x8 r0, r1, r2, r3;
#pragma unroll
    for (int k = 0; k < 8; ++k) { r2[k] = 0; r3[k] = 0; }
    float n2 = 0.f;
    float xv[16];
#pragma unroll
    for (int k = 0; k < 16; ++k) {
        float fv = f[k * HW];
        xv[k] = -2.f * fv;
        unsigned short h = rne_bf16(fv);
        if (k < 8) r0[k] = (short)h; else r1[k - 8] = (short)h;
        float x = bf2f(h);
        n2 = fmaf(x, x, n2);
    }
    r2[0] = (short)0x3F80; r2[1] = (short)0x3F80;
    xn[p] = sqrtf(n2);
    if (x2T) {
        float4* o = (float4*)(x2T + (size_t)p * 16);
        o[0] = *(float4*)&xv[0];  o[1] = *(float4*)&xv[4];
        o[2] = *(float4*)&xv[8];  o[3] = *(float4*)&xv[12];
    }
    *(bf16x8*)(xb + ((size_t)0 * P_TOT + p) * 8) = r0;
    *(bf16x8*)(xb + ((size_t)1 * P_TOT + p) * 8) = r1;
    *(bf16x8*)(xb + ((size_t)2 * P_TOT + p) * 8) = r2;
    *(bf16x8*)(xb + ((size_t)3 * P_TOT + p) * 8) = r3;
}

// ---------------- pass A: MFMA approx, per-(pixel,chunk) min ---------------
__global__ __launch_bounds__(256)
void pass_a(const short* __restrict__ xb, const short* __restrict__ wb,
            float* __restrict__ chunkmin)
{
    __shared__ int4 wlds[4 * CV];
    const int c = blockIdx.y;
    const int4* wsrc = (const int4*)(wb + (size_t)c * 4 * CV * 8);
    for (int r = threadIdx.x; r < 4 * CV; r += 256) wlds[r] = wsrc[r];

    const int wid = threadIdx.x >> 6, lane = threadIdx.x & 63;
    const int q = lane >> 4, l15 = lane & 15;
    const int p0 = (blockIdx.x * 4 + wid) * PIXW;

    bf16x8 bfrag[TPW];
#pragma unroll
    for (int t = 0; t < TPW; ++t)
        bfrag[t] = *(const bf16x8*)(xb + ((size_t)q * P_TOT + p0 + t * 16 + l15) * 8);

    __syncthreads();

    f32x4 z = {0.f, 0.f, 0.f, 0.f};
    float run[TPW];
#pragma unroll
    for (int t = 0; t < TPW; ++t) run[t] = 3.0e38f;

    const short* wl = (const short*)wlds + (size_t)q * CV * 8;
#pragma unroll 2
    for (int s = 0; s < CV / 16; ++s) {
        bf16x8 a = *(const bf16x8*)(wl + (s * 16 + l15) * 8);
        f32x4 acc[TPW];
#pragma unroll
        for (int t = 0; t < TPW; ++t)
            acc[t] = __builtin_amdgcn_mfma_f32_16x16x32_bf16(a, bfrag[t], z, 0, 0, 0);
#pragma unroll
        for (int t = 0; t < TPW; ++t) {
            float m = fminf(fminf(acc[t][0], acc[t][1]), acc[t][2]);   // v_min3
            run[t] = fminf(fminf(run[t], acc[t][3]), m);               // v_min3
        }
    }
#pragma unroll
    for (int t = 0; t < TPW; ++t) {
        float v = run[t];
        v = fminf(v, __shfl_xor(v, 16, 64));
        v = fminf(v, __shfl_xor(v, 32, 64));
        if (lane < 16)
            chunkmin[(size_t)c * P_TOT + p0 + t * 16 + lane] = v;
    }
}

// ---------------- pass B1: thresholds + per-chunk candidate buckets --------
__global__ __launch_bounds__(256)
void pass_b1(const float* __restrict__ chunkmin, const float* __restrict__ xn,
             const unsigned* __restrict__ n2max,
             unsigned* __restrict__ cnt, unsigned* __restrict__ buckets)
{
    int p = blockIdx.x * 256 + threadIdx.x;
    float cm[NCH];
    float gm = 3.0e38f;
#pragma unroll
    for (int c = 0; c < NCH; ++c) {
        cm[c] = chunkmin[(size_t)c * P_TOT + p];
        gm = fminf(gm, cm[c]);
    }
    float Wm = sqrtf(__uint_as_float(*n2max));
    float T = gm + 2.f * (0.004f * xn[p] * Wm + 1e-3f);
#pragma unroll
    for (int c = 0; c < NCH; ++c) {
        if (cm[c] <= T) {
            unsigned slot = atomicAdd(&cnt[c], 1u);
            buckets[(size_t)c * P_TOT + slot] = (unsigned)p;
        }
    }
}

// ---------------- pass B2: wave-per-candidate exact fp32 refine ------------
__global__ __launch_bounds__(256)
void pass_b2(const unsigned* __restrict__ cnt, const unsigned* __restrict__ buckets,
             const float* __restrict__ ve, const float* __restrict__ c2buf,
             const float* __restrict__ x2T, unsigned long long* __restrict__ keys)
{
    __shared__ float wl[CV * 20];   // 40KB; row = 16 w + c2 + pad (80B stride)
    const int c = blockIdx.y;
    const int vbase = c * CV;
    const int rows = min(CV, V_TOT - vbase);
    for (int r = threadIdx.x; r < rows * 5; r += 256) {
        int v = r / 5, s = r % 5;
        if (s < 4)
            *(float4*)&wl[v * 20 + s * 4] =
                *(const float4*)(ve + (size_t)(vbase + v) * DIMS + s * 4);
        else
            wl[v * 20 + 16] = c2buf[vbase + v];
    }
    __syncthreads();

    const int wid = threadIdx.x >> 6, lane = threadIdx.x & 63;
    const unsigned n = cnt[c];
    for (unsigned i = blockIdx.x * 4 + wid; i < n; i += B2BX * 4) {
        const unsigned p = buckets[(size_t)c * P_TOT + i];
        const float4* xq = (const float4*)(x2T + (size_t)p * 16);
        const float4 xa = xq[0], xb4 = xq[1], xc = xq[2], xd = xq[3];
        unsigned long long best = ~0ull;
#pragma unroll
        for (int k = 0; k < 8; ++k) {
            int v = k * 64 + lane;
            if (v < rows) {
                const float* row = &wl[v * 20];
                float4 a  = *(const float4*)(row);
                float4 b4 = *(const float4*)(row + 4);
                float4 cc = *(const float4*)(row + 8);
                float4 d4 = *(const float4*)(row + 12);
                float s = row[16];
                s = fmaf(xa.x,  a.x,  s); s = fmaf(xa.y,  a.y,  s);
                s = fmaf(xa.z,  a.z,  s); s = fmaf(xa.w,  a.w,  s);
                s = fmaf(xb4.x, b4.x, s); s = fmaf(xb4.y, b4.y, s);
                s = fmaf(xb4.z, b4.z, s); s = fmaf(xb4.w, b4.w, s);
                s = fmaf(xc.x,  cc.x, s); s = fmaf(xc.y,  cc.y, s);
                s = fmaf(xc.z,  cc.z, s); s = fmaf(xc.w,  cc.w, s);
                s = fmaf(xd.x,  d4.x, s); s = fmaf(xd.y,  d4.y, s);
                s = fmaf(xd.z,  d4.z, s); s = fmaf(xd.w,  d4.w, s);
                unsigned long long key =
                    ((unsigned long long)sortable(s) << 32) | (unsigned)(vbase + v);
                best = key < best ? key : best;
            }
        }
#pragma unroll
        for (int off = 32; off; off >>= 1) {
            unsigned long long o = __shfl_xor(best, off, 64);
            best = o < best ? o : best;
        }
        if (lane == 0) atomicMin(&keys[p], best);
    }
}

// ---------------- pass B serial (round-2 proven, mid-ws fallback) ----------
__global__ __launch_bounds__(256)
void pass_b(const float* __restrict__ chunkmin, const float* __restrict__ xn,
            const unsigned* __restrict__ n2max, const float* __restrict__ c2buf,
            const float* __restrict__ feats, const float* __restrict__ ve,
            unsigned long long* __restrict__ keys)
{
    __shared__ float cmins[NCH][64];
    __shared__ float Tsh[64];
    __shared__ float xlds[16][64];
    __shared__ unsigned long long candm[NCH];
    const int p0 = blockIdx.x * 64;
    const int tid = threadIdx.x;
    for (int i = tid; i < NCH * 64; i += 256) {
        int c = i >> 6, t = i & 63;
        cmins[c][t] = chunkmin[(size_t)c * P_TOT + p0 + t];
    }
    for (int i = tid; i < 16 * 64; i += 256) {
        int k = i >> 6, t = i & 63;
        int p = p0 + t, b = p / HW, hw = p - b * HW;
        xlds[k][t] = -2.f * feats[((size_t)b * DIMS + k) * HW + hw];
    }
    __syncthreads();
    if (tid < 64) {
        float gm = 3.0e38f;
        for (int c = 0; c < NCH; ++c) gm = fminf(gm, cmins[c][tid]);
        float Wm = sqrtf(__uint_as_float(*n2max));
        float mp = 0.004f * xn[p0 + tid] * Wm + 1e-3f;
        Tsh[tid] = gm + 2.f * mp;
    }
    __syncthreads();
    if (tid < 64) {
        for (int c = 0; c < NCH; ++c) {
            unsigned long long m = __ballot(cmins[c][tid] <= Tsh[tid]);
            if (tid == 0) candm[c] = m;
        }
    }
    __syncthreads();
    for (int c = 0; c < NCH; ++c) {
        unsigned long long m = candm[c];
        while (m) {
            int t = __ffsll((unsigned long long)m) - 1;
            m &= m - 1;
            unsigned long long best = ~0ull;
            int vend = min((c + 1) * CV, V_TOT);
            for (int v = c * CV + tid; v < vend; v += 256) {
                const float4* w4 = (const float4*)(ve + (size_t)v * DIMS);
                float4 a = w4[0], b4 = w4[1], cc = w4[2], d4 = w4[3];
                float s = c2buf[v];
                s = fmaf(xlds[0][t],  a.x,  s); s = fmaf(xlds[1][t],  a.y,  s);
                s = fmaf(xlds[2][t],  a.z,  s); s = fmaf(xlds[3][t],  a.w,  s);
                s = fmaf(xlds[4][t],  b4.x, s); s = fmaf(xlds[5][t],  b4.y, s);
                s = fmaf(xlds[6][t],  b4.z, s); s = fmaf(xlds[7][t],  b4.w, s);
                s = fmaf(xlds[8][t],  cc.x, s); s = fmaf(xlds[9][t],  cc.y, s);
                s = fmaf(xlds[10][t], cc.z, s); s = fmaf(xlds[11][t], cc.w, s);
                s = fmaf(xlds[12][t], d4.x, s); s = fmaf(xlds[13][t], d4.y, s);
                s = fmaf(xlds[14][t], d4.z, s); s = fmaf(xlds[15][t], d4.w, s);
                unsigned long long key =
                    ((unsigned long long)sortable(s) << 32) | (unsigned)v;
                best = (key < best) ? key : best;
            }
            for (int off = 32; off; off >>= 1) {
                unsigned long long o = __shfl_xor(best, off, 64);
                best = (o < best) ? o : best;
            }
            if ((tid & 63) == 0) atomicMin(&keys[p0 + t], best);
        }
    }
}

__global__ void cse_finalize(const unsigned long long* __restrict__ keys,
                             float* __restrict__ out)
{
    int p = blockIdx.x * 256 + threadIdx.x;
    if (p < P_TOT)
        out[FEAT_N + p] = (float)(unsigned)(keys[p] & 0xffffffffull);
}

// ---------------- fallback (round-1 proven VALU kernel) --------------------
__global__ __launch_bounds__(256, 2)
void cse_argmin(const float* __restrict__ feats, const float* __restrict__ ve,
                unsigned long long* __restrict__ keys)
{
    __shared__ float4 se4[VC * 4];
    __shared__ float  sh[VC];
    const int j = blockIdx.y, v0 = j * VC;
    const int cnt = min(VC, V_TOT - v0);
    for (int t = threadIdx.x; t < cnt; t += 256) {
        const float4* w4 = (const float4*)(ve + (size_t)(v0 + t) * DIMS);
        float4 a = w4[0], b = w4[1], c = w4[2], d = w4[3];
        float h = a.x*a.x + a.y*a.y + a.z*a.z + a.w*a.w
                + b.x*b.x + b.y*b.y + b.z*b.z + b.w*b.w
                + c.x*c.x + c.y*c.y + c.z*c.z + c.w*c.w
                + d.x*d.x + d.y*d.y + d.z*d.z + d.w*d.w;
        se4[t*4+0] = make_float4(-a.x,-a.y,-a.z,-a.w);
        se4[t*4+1] = make_float4(-b.x,-b.y,-b.z,-b.w);
        se4[t*4+2] = make_float4(-c.x,-c.y,-c.z,-c.w);
        se4[t*4+3] = make_float4(-d.x,-d.y,-d.z,-d.w);
        sh[t] = 0.5f * h;
    }
    __syncthreads();
    const int p0 = (blockIdx.x * 256 + threadIdx.x) * PPT;
    const int bb = p0 / HW, hw = p0 - bb * HW;
    const float* fb = feats + (size_t)bb * (DIMS * HW) + hw;
    float4 x[DIMS];
#pragma unroll
    for (int d = 0; d < DIMS; ++d) x[d] = *(const float4*)(fb + d * HW);
    float m0b = 3.4e38f, m1b = 3.4e38f, m2b = 3.4e38f, m3b = 3.4e38f;
    int i0 = 0, i1 = 0, i2 = 0, i3 = 0;
#pragma unroll 2
    for (int v = 0; v < cnt; ++v) {
        const float h = sh[v];
        float m0 = h, m1 = h, m2 = h, m3 = h;
#pragma unroll
        for (int k = 0; k < 4; ++k) {
            const float4 nw = se4[v*4 + k];
            const float4 xa = x[4*k+0], xb = x[4*k+1], xc = x[4*k+2], xd = x[4*k+3];
            m0 = fmaf(nw.x, xa.x, m0); m0 = fmaf(nw.y, xb.x, m0);
            m0 = fmaf(nw.z, xc.x, m0); m0 = fmaf(nw.w, xd.x, m0);
            m1 = fmaf(nw.x, xa.y, m1); m1 = fmaf(nw.y, xb.y, m1);
            m1 = fmaf(nw.z, xc.y, m1); m1 = fmaf(nw.w, xd.y, m1);
            m2 = fmaf(nw.x, xa.z, m2); m2 = fmaf(nw.y, xb.z, m2);
            m2 = fmaf(nw.z, xc.z, m2); m2 = fmaf(nw.w, xd.z, m2);
            m3 = fmaf(nw.x, xa.w, m3); m3 = fmaf(nw.y, xb.w, m3);
            m3 = fmaf(nw.z, xc.w, m3); m3 = fmaf(nw.w, xd.w, m3);
        }
        const int vg = v0 + v;
        bool c0 = m0 < m0b; m0b = c0 ? m0 : m0b; i0 = c0 ? vg : i0;
        bool c1 = m1 < m1b; m1b = c1 ? m1 : m1b; i1 = c1 ? vg : i1;
        bool c2 = m2 < m2b; m2b = c2 ? m2 : m2b; i2 = c2 ? vg : i2;
        bool c3 = m3 < m3b; m3b = c3 ? m3 : m3b; i3 = c3 ? vg : i3;
    }
    unsigned long long* kp = keys + p0;
    float mb[PPT] = { m0b, m1b, m2b, m3b };
    int   ib[PPT] = { i0, i1, i2, i3 };
#pragma unroll
    for (int p = 0; p < PPT; ++p) {
        unsigned long long key = ((unsigned long long)sortable(mb[p]) << 32) | (unsigned)ib[p];
        atomicMin(&kp[p], key);
    }
}

extern "C" void kernel_launch(void* const* d_in, const int* in_sizes, int n_in,
                              void* d_out, int out_size, void* d_ws, size_t ws_size,
                              hipStream_t stream)
{
    const float* feats = (const float*)d_in[0];
    const float* ve    = (const float*)d_in[1];
    float* out = (float*)d_out;
    char* ws = (char*)d_ws;

    hipMemcpyAsync(out, feats, (size_t)FEAT_N * sizeof(float),
                   hipMemcpyDeviceToDevice, stream);

    if (ws_size >= WS_BIG) {
        unsigned long long* keys = (unsigned long long*)(ws + OFF_KEYS);
        unsigned* n2max = (unsigned*)(ws + OFF_N2MAX);
        float* c2buf = (float*)(ws + OFF_C2);
        float* xnorm = (float*)(ws + OFF_XN);
        float* x2T   = (float*)(ws + OFF_X2T);
        short* xbuf  = (short*)(ws + OFF_XB);
        short* wbuf  = (short*)(ws + OFF_WB);
        float* cmin  = (float*)(ws + OFF_CM);
        unsigned* cnt = (unsigned*)(ws + OFF_CNT);
        unsigned* bkt = (unsigned*)(ws + OFF_BKT);

        hipMemsetAsync(keys, 0xFF, (size_t)P_TOT * 8, stream);
        hipMemsetAsync(n2max, 0, 4, stream);
        hipMemsetAsync(cnt, 0, NCH * 4, stream);

        prep_v<<<VPAD / 256, 256, 0, stream>>>(ve, wbuf, c2buf, n2max);
        prep_x<<<P_TOT / 256, 256, 0, stream>>>(feats, xbuf, xnorm, x2T);
        pass_a<<<dim3(P_TOT / (4 * PIXW), NCH), 256, 0, stream>>>(xbuf, wbuf, cmin);
        pass_b1<<<P_TOT / 256, 256, 0, stream>>>(cmin, xnorm, n2max, cnt, bkt);
        pass_b2<<<dim3(B2BX, NCH), 256, 0, stream>>>(cnt, bkt, ve, c2buf, x2T, keys);
        cse_finalize<<<(P_TOT + 255) / 256, 256, 0, stream>>>(keys, out);
    } else if (ws_size >= WS_MID) {
        unsigned long long* keys = (unsigned long long*)(ws + MOFF_KEYS);
        unsigned* n2max = (unsigned*)(ws + MOFF_N2MAX);
        float* c2buf = (float*)(ws + MOFF_C2);
        float* xnorm = (float*)(ws + MOFF_XN);
        short* xbuf  = (short*)(ws + MOFF_XB);
        short* wbuf  = (short*)(ws + MOFF_WB);
        float* cmin  = (float*)(ws + MOFF_CM);

        hipMemsetAsync(keys, 0xFF, (size_t)P_TOT * 8, stream);
        hipMemsetAsync(n2max, 0, 4, stream);

        prep_v<<<VPAD / 256, 256, 0, stream>>>(ve, wbuf, c2buf, n2max);
        prep_x<<<P_TOT / 256, 256, 0, stream>>>(feats, xbuf, xnorm, nullptr);
        pass_a<<<dim3(P_TOT / (4 * PIXW), NCH), 256, 0, stream>>>(xbuf, wbuf, cmin);
        pass_b<<<P_TOT / 64, 256, 0, stream>>>(cmin, xnorm, n2max, c2buf,
                                               feats, ve, keys);
        cse_finalize<<<(P_TOT + 255) / 256, 256, 0, stream>>>(keys, out);
    } else {
        unsigned long long* keys = (unsigned long long*)d_ws;
        hipMemsetAsync(d_ws, 0xFF, (size_t)P_TOT * 8, stream);
        cse_argmin<<<dim3(P_TOT / (256 * PPT), NV), 256, 0, stream>>>(feats, ve, keys);
        cse_finalize<<<(P_TOT + 255) / 256, 256, 0, stream>>>(keys, out);
    }
}

// Round 7
// 583.079 us; speedup vs baseline: 1.0114x; 1.0114x over previous
//
#include <hip/hip_runtime.h>
#include <stdint.h>

// CSENet: per-pixel argmin over 27554 vertex embeddings (16-dim, fp32).
// (A) bf16 MFMA approx scores s~ = c2 - 2 x.w (c2 folded into K slots),
//     min-only reduce -> per-(pixel,chunk) min table.
// (B1) per-pixel threshold (provable bf16 margin), scatter candidates into
//      per-chunk buckets. Wave-aggregated atomicAdd (ballot+prefix) -- the
//      naive per-lane atomicAdd-with-return serialized ~1M same-address RMWs
//      and cost 352us with all pipes idle (round-6 counters).
// (B2) one wave per candidate (pixel,chunk): exact fp32 rescan of the chunk
//      from LDS (80B row stride -> conflict-free), packed u64 atomicMin.

#define DIMS   16
#define HW     12544
#define P_TOT  50176
#define V_TOT  27554
#define FEAT_N 802816

#define CV     512
#define NCH    54
#define VPAD   (NCH*CV)
#define PIXW   128
#define TPW    8
#define B2BX   32

// fallback (round-1) path
#define NV     64
#define VC     431
#define PPT    4

typedef __attribute__((ext_vector_type(8))) short bf16x8;
typedef __attribute__((ext_vector_type(4))) float f32x4;

// ---- big-ws layout (bytes) ----
#define OFF_KEYS  0ul
#define OFF_N2MAX 401408ul
#define OFF_C2    401664ul
#define OFF_XN    512000ul
#define OFF_X2T   712704ul
#define OFF_XB    3923968ul
#define OFF_WB    7135232ul
#define OFF_CM    8904704ul
#define OFF_CNT   19742720ul
#define OFF_BKT   19742976ul
#define WS_BIG    30580992ul
// ---- mid-ws layout (round-2, proven) ----
#define MOFF_KEYS  0ul
#define MOFF_N2MAX 401408ul
#define MOFF_C2    405504ul
#define MOFF_XN    516096ul
#define MOFF_XB    716800ul
#define MOFF_WB    3928064ul
#define MOFF_CM    5697536ul
#define WS_MID     16535552ul

__device__ __forceinline__ unsigned short rne_bf16(float f) {
    unsigned u = __float_as_uint(f);
    return (unsigned short)((u + 0x7FFFu + ((u >> 16) & 1u)) >> 16);
}
__device__ __forceinline__ float bf2f(unsigned short h) {
    return __uint_as_float(((unsigned)h) << 16);
}
__device__ __forceinline__ unsigned sortable(float s) {
    unsigned u = __float_as_uint(s);
    return (u & 0x80000000u) ? ~u : (u | 0x80000000u);
}

// ---------------- prep: vertices -> bf16 A-fragments + c2 + max|w~|^2 -----
__global__ void prep_v(const float* __restrict__ ve, short* __restrict__ wb,
                       float* __restrict__ c2buf, unsigned* __restrict__ n2max)
{
    int v = blockIdx.x * 256 + threadIdx.x;
    if (v >= VPAD) return;
    int c = v / CV, vl = v % CV;
    bf16x8 r0, r1, r2, r3;
#pragma unroll
    for (int k = 0; k < 8; ++k) { r2[k] = 0; r3[k] = 0; }
    if (v < V_TOT) {
        const float4* w4 = (const float4*)(ve + (size_t)v * DIMS);
        float w[16];
        *(float4*)&w[0] = w4[0]; *(float4*)&w[4]  = w4[1];
        *(float4*)&w[8] = w4[2]; *(float4*)&w[12] = w4[3];
        float c2 = 0.f;
#pragma unroll
        for (int k = 0; k < 16; ++k) c2 = fmaf(w[k], w[k], c2);
        c2buf[v] = c2;
        float n2 = 0.f;
#pragma unroll
        for (int k = 0; k < 16; ++k) {
            unsigned short h = rne_bf16(-2.f * w[k]);
            if (k < 8) r0[k] = (short)h; else r1[k - 8] = (short)h;
            float f = bf2f(h);
            n2 = fmaf(f, f, n2);
        }
        atomicMax(n2max, __float_as_uint(n2));
        unsigned short hi = rne_bf16(c2);
        unsigned short lo = rne_bf16(c2 - bf2f(hi));
        r2[0] = (short)hi; r2[1] = (short)lo;
    } else {
#pragma unroll
        for (int k = 0; k < 8; ++k) { r0[k] = 0; r1[k] = 0; }
        r2[0] = (short)rne_bf16(30000.f);   // padding: huge score, never wins
    }
    *(bf16x8*)(wb + (((size_t)c * 4 + 0) * CV + vl) * 8) = r0;
    *(bf16x8*)(wb + (((size_t)c * 4 + 1) * CV + vl) * 8) = r1;
    *(bf16x8*)(wb + (((size_t)c * 4 + 2) * CV + vl) * 8) = r2;
    *(bf16x8*)(wb + (((size_t)c * 4 + 3) * CV + vl) * 8) = r3;
}

// ------- prep: pixels -> bf16 B-fragments + |x~| (+ optional fp32 -2x) -----
__global__ void prep_x(const float* __restrict__ feats, short* __restrict__ xb,
                       float* __restrict__ xn, float* __restrict__ x2T)
{
    int p = blockIdx.x * 256 + threadIdx.x;
    int b = p / HW, hw = p - b * HW;
    const float* f = feats + (size_t)b * DIMS * HW + hw;
    bf16x8 r0, r1, r2, r3;
#pragma unroll
    for (int k = 0; k < 8; ++k) { r2[k] = 0; r3[k] = 0; }
    float n2 = 0.f;
    float xv[16];
#pragma unroll
    for (int k = 0; k < 16; ++k) {
        float fv = f[k * HW];
        xv[k] = -2.f * fv;
        unsigned short h = rne_bf16(fv);
        if (k < 8) r0[k] = (short)h; else r1[k - 8] = (short)h;
        float x = bf2f(h);
        n2 = fmaf(x, x, n2);
    }
    r2[0] = (short)0x3F80; r2[1] = (short)0x3F80;
    xn[p] = sqrtf(n2);
    if (x2T) {
        float4* o = (float4*)(x2T + (size_t)p * 16);
        o[0] = *(float4*)&xv[0];  o[1] = *(float4*)&xv[4];
        o[2] = *(float4*)&xv[8];  o[3] = *(float4*)&xv[12];
    }
    *(bf16x8*)(xb + ((size_t)0 * P_TOT + p) * 8) = r0;
    *(bf16x8*)(xb + ((size_t)1 * P_TOT + p) * 8) = r1;
    *(bf16x8*)(xb + ((size_t)2 * P_TOT + p) * 8) = r2;
    *(bf16x8*)(xb + ((size_t)3 * P_TOT + p) * 8) = r3;
}

// ---------------- pass A: MFMA approx, per-(pixel,chunk) min ---------------
__global__ __launch_bounds__(256)
void pass_a(const short* __restrict__ xb, const short* __restrict__ wb,
            float* __restrict__ chunkmin)
{
    __shared__ int4 wlds[4 * CV];
    const int c = blockIdx.y;
    const int4* wsrc = (const int4*)(wb + (size_t)c * 4 * CV * 8);
    for (int r = threadIdx.x; r < 4 * CV; r += 256) wlds[r] = wsrc[r];

    const int wid = threadIdx.x >> 6, lane = threadIdx.x & 63;
    const int q = lane >> 4, l15 = lane & 15;
    const int p0 = (blockIdx.x * 4 + wid) * PIXW;

    bf16x8 bfrag[TPW];
#pragma unroll
    for (int t = 0; t < TPW; ++t)
        bfrag[t] = *(const bf16x8*)(xb + ((size_t)q * P_TOT + p0 + t * 16 + l15) * 8);

    __syncthreads();

    f32x4 z = {0.f, 0.f, 0.f, 0.f};
    float run[TPW];
#pragma unroll
    for (int t = 0; t < TPW; ++t) run[t] = 3.0e38f;

    const short* wl = (const short*)wlds + (size_t)q * CV * 8;
#pragma unroll 2
    for (int s = 0; s < CV / 16; ++s) {
        bf16x8 a = *(const bf16x8*)(wl + (s * 16 + l15) * 8);
        f32x4 acc[TPW];
#pragma unroll
        for (int t = 0; t < TPW; ++t)
            acc[t] = __builtin_amdgcn_mfma_f32_16x16x32_bf16(a, bfrag[t], z, 0, 0, 0);
#pragma unroll
        for (int t = 0; t < TPW; ++t) {
            float m = fminf(fminf(acc[t][0], acc[t][1]), acc[t][2]);   // v_min3
            run[t] = fminf(fminf(run[t], acc[t][3]), m);               // v_min3
        }
    }
#pragma unroll
    for (int t = 0; t < TPW; ++t) {
        float v = run[t];
        v = fminf(v, __shfl_xor(v, 16, 64));
        v = fminf(v, __shfl_xor(v, 32, 64));
        if (lane < 16)
            chunkmin[(size_t)c * P_TOT + p0 + t * 16 + lane] = v;
    }
}

// -------- pass B1: thresholds + wave-aggregated candidate buckets ----------
__global__ __launch_bounds__(256)
void pass_b1(const float* __restrict__ chunkmin, const float* __restrict__ xn,
             const unsigned* __restrict__ n2max,
             unsigned* __restrict__ cnt, unsigned* __restrict__ buckets)
{
    const int p = blockIdx.x * 256 + threadIdx.x;
    const int lane = threadIdx.x & 63;
    float cm[NCH];
    float gm = 3.0e38f;
#pragma unroll
    for (int c = 0; c < NCH; ++c) {
        cm[c] = chunkmin[(size_t)c * P_TOT + p];
        gm = fminf(gm, cm[c]);
    }
    float Wm = sqrtf(__uint_as_float(*n2max));
    float T = gm + 2.f * (0.004f * xn[p] * Wm + 1e-3f);
#pragma unroll
    for (int c = 0; c < NCH; ++c) {
        bool want = (cm[c] <= T);
        unsigned long long m = __ballot(want);
        if (!m) continue;
        int nw = __popcll(m);
        int leader = __ffsll(m) - 1;
        unsigned base = 0;
        if (lane == leader) base = atomicAdd(&cnt[c], (unsigned)nw);
        base = __shfl(base, leader, 64);           // one RMW per wave, not 64
        if (want) {
            unsigned pos = (unsigned)__popcll(m & ((1ull << lane) - 1ull));
            buckets[(size_t)c * P_TOT + base + pos] = (unsigned)p;
        }
    }
}

// ---------------- pass B2: wave-per-candidate exact fp32 refine ------------
__global__ __launch_bounds__(256)
void pass_b2(const unsigned* __restrict__ cnt, const unsigned* __restrict__ buckets,
             const float* __restrict__ ve, const float* __restrict__ c2buf,
             const float* __restrict__ x2T, unsigned long long* __restrict__ keys)
{
    __shared__ float wl[CV * 20];   // 40KB; row = 16 w + c2 + pad (80B stride)
    const int c = blockIdx.y;
    const int vbase = c * CV;
    const int rows = min(CV, V_TOT - vbase);
    for (int r = threadIdx.x; r < rows * 5; r += 256) {
        int v = r / 5, s = r % 5;
        if (s < 4)
            *(float4*)&wl[v * 20 + s * 4] =
                *(const float4*)(ve + (size_t)(vbase + v) * DIMS + s * 4);
        else
            wl[v * 20 + 16] = c2buf[vbase + v];
    }
    __syncthreads();

    const int wid = threadIdx.x >> 6, lane = threadIdx.x & 63;
    const unsigned n = cnt[c];
    for (unsigned i = blockIdx.x * 4 + wid; i < n; i += B2BX * 4) {
        const unsigned p = buckets[(size_t)c * P_TOT + i];
        const float4* xq = (const float4*)(x2T + (size_t)p * 16);
        const float4 xa = xq[0], xb4 = xq[1], xc = xq[2], xd = xq[3];
        unsigned long long best = ~0ull;
#pragma unroll
        for (int k = 0; k < 8; ++k) {
            int v = k * 64 + lane;
            if (v < rows) {
                const float* row = &wl[v * 20];
                float4 a  = *(const float4*)(row);
                float4 b4 = *(const float4*)(row + 4);
                float4 cc = *(const float4*)(row + 8);
                float4 d4 = *(const float4*)(row + 12);
                float s = row[16];
                s = fmaf(xa.x,  a.x,  s); s = fmaf(xa.y,  a.y,  s);
                s = fmaf(xa.z,  a.z,  s); s = fmaf(xa.w,  a.w,  s);
                s = fmaf(xb4.x, b4.x, s); s = fmaf(xb4.y, b4.y, s);
                s = fmaf(xb4.z, b4.z, s); s = fmaf(xb4.w, b4.w, s);
                s = fmaf(xc.x,  cc.x, s); s = fmaf(xc.y,  cc.y, s);
                s = fmaf(xc.z,  cc.z, s); s = fmaf(xc.w,  cc.w, s);
                s = fmaf(xd.x,  d4.x, s); s = fmaf(xd.y,  d4.y, s);
                s = fmaf(xd.z,  d4.z, s); s = fmaf(xd.w,  d4.w, s);
                unsigned long long key =
                    ((unsigned long long)sortable(s) << 32) | (unsigned)(vbase + v);
                best = key < best ? key : best;
            }
        }
#pragma unroll
        for (int off = 32; off; off >>= 1) {
            unsigned long long o = __shfl_xor(best, off, 64);
            best = o < best ? o : best;
        }
        if (lane == 0) atomicMin(&keys[p], best);
    }
}

// ---------------- pass B serial (round-2 proven, mid-ws fallback) ----------
__global__ __launch_bounds__(256)
void pass_b(const float* __restrict__ chunkmin, const float* __restrict__ xn,
            const unsigned* __restrict__ n2max, const float* __restrict__ c2buf,
            const float* __restrict__ feats, const float* __restrict__ ve,
            unsigned long long* __restrict__ keys)
{
    __shared__ float cmins[NCH][64];
    __shared__ float Tsh[64];
    __shared__ float xlds[16][64];
    __shared__ unsigned long long candm[NCH];
    const int p0 = blockIdx.x * 64;
    const int tid = threadIdx.x;
    for (int i = tid; i < NCH * 64; i += 256) {
        int c = i >> 6, t = i & 63;
        cmins[c][t] = chunkmin[(size_t)c * P_TOT + p0 + t];
    }
    for (int i = tid; i < 16 * 64; i += 256) {
        int k = i >> 6, t = i & 63;
        int p = p0 + t, b = p / HW, hw = p - b * HW;
        xlds[k][t] = -2.f * feats[((size_t)b * DIMS + k) * HW + hw];
    }
    __syncthreads();
    if (tid < 64) {
        float gm = 3.0e38f;
        for (int c = 0; c < NCH; ++c) gm = fminf(gm, cmins[c][tid]);
        float Wm = sqrtf(__uint_as_float(*n2max));
        float mp = 0.004f * xn[p0 + tid] * Wm + 1e-3f;
        Tsh[tid] = gm + 2.f * mp;
    }
    __syncthreads();
    if (tid < 64) {
        for (int c = 0; c < NCH; ++c) {
            unsigned long long m = __ballot(cmins[c][tid] <= Tsh[tid]);
            if (tid == 0) candm[c] = m;
        }
    }
    __syncthreads();
    for (int c = 0; c < NCH; ++c) {
        unsigned long long m = candm[c];
        while (m) {
            int t = __ffsll((unsigned long long)m) - 1;
            m &= m - 1;
            unsigned long long best = ~0ull;
            int vend = min((c + 1) * CV, V_TOT);
            for (int v = c * CV + tid; v < vend; v += 256) {
                const float4* w4 = (const float4*)(ve + (size_t)v * DIMS);
                float4 a = w4[0], b4 = w4[1], cc = w4[2], d4 = w4[3];
                float s = c2buf[v];
                s = fmaf(xlds[0][t],  a.x,  s); s = fmaf(xlds[1][t],  a.y,  s);
                s = fmaf(xlds[2][t],  a.z,  s); s = fmaf(xlds[3][t],  a.w,  s);
                s = fmaf(xlds[4][t],  b4.x, s); s = fmaf(xlds[5][t],  b4.y, s);
                s = fmaf(xlds[6][t],  b4.z, s); s = fmaf(xlds[7][t],  b4.w, s);
                s = fmaf(xlds[8][t],  cc.x, s); s = fmaf(xlds[9][t],  cc.y, s);
                s = fmaf(xlds[10][t], cc.z, s); s = fmaf(xlds[11][t], cc.w, s);
                s = fmaf(xlds[12][t], d4.x, s); s = fmaf(xlds[13][t], d4.y, s);
                s = fmaf(xlds[14][t], d4.z, s); s = fmaf(xlds[15][t], d4.w, s);
                unsigned long long key =
                    ((unsigned long long)sortable(s) << 32) | (unsigned)v;
                best = (key < best) ? key : best;
            }
            for (int off = 32; off; off >>= 1) {
                unsigned long long o = __shfl_xor(best, off, 64);
                best = (o < best) ? o : best;
            }
            if ((tid & 63) == 0) atomicMin(&keys[p0 + t], best);
        }
    }
}

__global__ void cse_finalize(const unsigned long long* __restrict__ keys,
                             float* __restrict__ out)
{
    int p = blockIdx.x * 256 + threadIdx.x;
    if (p < P_TOT)
        out[FEAT_N + p] = (float)(unsigned)(keys[p] & 0xffffffffull);
}

// ---------------- fallback (round-1 proven VALU kernel) --------------------
__global__ __launch_bounds__(256, 2)
void cse_argmin(const float* __restrict__ feats, const float* __restrict__ ve,
                unsigned long long* __restrict__ keys)
{
    __shared__ float4 se4[VC * 4];
    __shared__ float  sh[VC];
    const int j = blockIdx.y, v0 = j * VC;
    const int cnt = min(VC, V_TOT - v0);
    for (int t = threadIdx.x; t < cnt; t += 256) {
        const float4* w4 = (const float4*)(ve + (size_t)(v0 + t) * DIMS);
        float4 a = w4[0], b = w4[1], c = w4[2], d = w4[3];
        float h = a.x*a.x + a.y*a.y + a.z*a.z + a.w*a.w
                + b.x*b.x + b.y*b.y + b.z*b.z + b.w*b.w
                + c.x*c.x + c.y*c.y + c.z*c.z + c.w*c.w
                + d.x*d.x + d.y*d.y + d.z*d.z + d.w*d.w;
        se4[t*4+0] = make_float4(-a.x,-a.y,-a.z,-a.w);
        se4[t*4+1] = make_float4(-b.x,-b.y,-b.z,-b.w);
        se4[t*4+2] = make_float4(-c.x,-c.y,-c.z,-c.w);
        se4[t*4+3] = make_float4(-d.x,-d.y,-d.z,-d.w);
        sh[t] = 0.5f * h;
    }
    __syncthreads();
    const int p0 = (blockIdx.x * 256 + threadIdx.x) * PPT;
    const int bb = p0 / HW, hw = p0 - bb * HW;
    const float* fb = feats + (size_t)bb * (DIMS * HW) + hw;
    float4 x[DIMS];
#pragma unroll
    for (int d = 0; d < DIMS; ++d) x[d] = *(const float4*)(fb + d * HW);
    float m0b = 3.4e38f, m1b = 3.4e38f, m2b = 3.4e38f, m3b = 3.4e38f;
    int i0 = 0, i1 = 0, i2 = 0, i3 = 0;
#pragma unroll 2
    for (int v = 0; v < cnt; ++v) {
        const float h = sh[v];
        float m0 = h, m1 = h, m2 = h, m3 = h;
#pragma unroll
        for (int k = 0; k < 4; ++k) {
            const float4 nw = se4[v*4 + k];
            const float4 xa = x[4*k+0], xb = x[4*k+1], xc = x[4*k+2], xd = x[4*k+3];
            m0 = fmaf(nw.x, xa.x, m0); m0 = fmaf(nw.y, xb.x, m0);
            m0 = fmaf(nw.z, xc.x, m0); m0 = fmaf(nw.w, xd.x, m0);
            m1 = fmaf(nw.x, xa.y, m1); m1 = fmaf(nw.y, xb.y, m1);
            m1 = fmaf(nw.z, xc.y, m1); m1 = fmaf(nw.w, xd.y, m1);
            m2 = fmaf(nw.x, xa.z, m2); m2 = fmaf(nw.y, xb.z, m2);
            m2 = fmaf(nw.z, xc.z, m2); m2 = fmaf(nw.w, xd.z, m2);
            m3 = fmaf(nw.x, xa.w, m3); m3 = fmaf(nw.y, xb.w, m3);
            m3 = fmaf(nw.z, xc.w, m3); m3 = fmaf(nw.w, xd.w, m3);
        }
        const int vg = v0 + v;
        bool c0 = m0 < m0b; m0b = c0 ? m0 : m0b; i0 = c0 ? vg : i0;
        bool c1 = m1 < m1b; m1b = c1 ? m1 : m1b; i1 = c1 ? vg : i1;
        bool c2 = m2 < m2b; m2b = c2 ? m2 : m2b; i2 = c2 ? vg : i2;
        bool c3 = m3 < m3b; m3b = c3 ? m3 : m3b; i3 = c3 ? vg : i3;
    }
    unsigned long long* kp = keys + p0;
    float mb[PPT] = { m0b, m1b, m2b, m3b };
    int   ib[PPT] = { i0, i1, i2, i3 };
#pragma unroll
    for (int p = 0; p < PPT; ++p) {
        unsigned long long key = ((unsigned long long)sortable(mb[p]) << 32) | (unsigned)ib[p];
        atomicMin(&kp[p], key);
    }
}

extern "C" void kernel_launch(void* const* d_in, const int* in_sizes, int n_in,
                              void* d_out, int out_size, void* d_ws, size_t ws_size,
                              hipStream_t stream)
{
    const float* feats = (const float*)d_in[0];
    const float* ve    = (const float*)d_in[1];
    float* out = (float*)d_out;
    char* ws = (char*)d_ws;

    hipMemcpyAsync(out, feats, (size_t)FEAT_N * sizeof(float),
                   hipMemcpyDeviceToDevice, stream);

    if (ws_size >= WS_BIG) {
        unsigned long long* keys = (unsigned long long*)(ws + OFF_KEYS);
        unsigned* n2max = (unsigned*)(ws + OFF_N2MAX);
        float* c2buf = (float*)(ws + OFF_C2);
        float* xnorm = (float*)(ws + OFF_XN);
        float* x2T   = (float*)(ws + OFF_X2T);
        short* xbuf  = (short*)(ws + OFF_XB);
        short* wbuf  = (short*)(ws + OFF_WB);
        float* cmin  = (float*)(ws + OFF_CM);
        unsigned* cnt = (unsigned*)(ws + OFF_CNT);
        unsigned* bkt = (unsigned*)(ws + OFF_BKT);

        hipMemsetAsync(keys, 0xFF, (size_t)P_TOT * 8, stream);
        hipMemsetAsync(n2max, 0, 4, stream);
        hipMemsetAsync(cnt, 0, NCH * 4, stream);

        prep_v<<<VPAD / 256, 256, 0, stream>>>(ve, wbuf, c2buf, n2max);
        prep_x<<<P_TOT / 256, 256, 0, stream>>>(feats, xbuf, xnorm, x2T);
        pass_a<<<dim3(P_TOT / (4 * PIXW), NCH), 256, 0, stream>>>(xbuf, wbuf, cmin);
        pass_b1<<<P_TOT / 256, 256, 0, stream>>>(cmin, xnorm, n2max, cnt, bkt);
        pass_b2<<<dim3(B2BX, NCH), 256, 0, stream>>>(cnt, bkt, ve, c2buf, x2T, keys);
        cse_finalize<<<(P_TOT + 255) / 256, 256, 0, stream>>>(keys, out);
    } else if (ws_size >= WS_MID) {
        unsigned long long* keys = (unsigned long long*)(ws + MOFF_KEYS);
        unsigned* n2max = (unsigned*)(ws + MOFF_N2MAX);
        float* c2buf = (float*)(ws + MOFF_C2);
        float* xnorm = (float*)(ws + MOFF_XN);
        short* xbuf  = (short*)(ws + MOFF_XB);
        short* wbuf  = (short*)(ws + MOFF_WB);
        float* cmin  = (float*)(ws + MOFF_CM);

        hipMemsetAsync(keys, 0xFF, (size_t)P_TOT * 8, stream);
        hipMemsetAsync(n2max, 0, 4, stream);

        prep_v<<<VPAD / 256, 256, 0, stream>>>(ve, wbuf, c2buf, n2max);
        prep_x<<<P_TOT / 256, 256, 0, stream>>>(feats, xbuf, xnorm, nullptr);
        pass_a<<<dim3(P_TOT / (4 * PIXW), NCH), 256, 0, stream>>>(xbuf, wbuf, cmin);
        pass_b<<<P_TOT / 64, 256, 0, stream>>>(cmin, xnorm, n2max, c2buf,
                                               feats, ve, keys);
        cse_finalize<<<(P_TOT + 255) / 256, 256, 0, stream>>>(keys, out);
    } else {
        unsigned long long* keys = (unsigned long long*)d_ws;
        hipMemsetAsync(d_ws, 0xFF, (size_t)P_TOT * 8, stream);
        cse_argmin<<<dim3(P_TOT / (256 * PPT), NV), 256, 0, stream>>>(feats, ve, keys);
        cse_finalize<<<(P_TOT + 255) / 256, 256, 0, stream>>>(keys, out);
    }
}

// Round 8
// 243.317 us; speedup vs baseline: 2.4238x; 2.3964x over previous
//
#include <hip/hip_runtime.h>
#include <stdint.h>

// CSENet: per-pixel argmin over 27554 vertex embeddings (16-dim, fp32).
// (A) bf16 MFMA approx scores s~ = c2 - 2 x.w, min-reduce -> chunkmin table.
// (B1) per-pixel threshold (provable bf16 margin) -> per-chunk buckets.
//      HISTORY: per-lane atomicAdd (r6, 352us) and wave-aggregated atomicAdd
//      (r7, 357us) were BOTH bound by same-cacheline device-atomic
//      serialization: 54 counters in 2 cachelines -> 2 serial RMW chains.
//      Fix: 128B-padded counters (54 parallel chains) + per-block LDS
//      aggregation (one global RMW per block per chunk, ~10K total).
// (B2) one wave per candidate (pixel,chunk): exact fp32 rescan from LDS,
//      packed u64 atomicMin(keys[p]) -- order-independent.

#define DIMS   16
#define HW     12544
#define P_TOT  50176
#define V_TOT  27554
#define FEAT_N 802816

#define CV     512
#define NCH    54
#define VPAD   (NCH*CV)
#define PIXW   128
#define TPW    8
#define B2BX   32
#define CNTSTRIDE 32          // u32s per chunk counter: 128B = own cacheline

// fallback (round-1) path
#define NV     64
#define VC     431
#define PPT    4

typedef __attribute__((ext_vector_type(8))) short bf16x8;
typedef __attribute__((ext_vector_type(4))) float f32x4;

// ---- big-ws layout (bytes) ----
#define OFF_KEYS  0ul
#define OFF_N2MAX 401408ul
#define OFF_C2    401664ul
#define OFF_XN    512000ul
#define OFF_X2T   712704ul
#define OFF_XB    3923968ul     // bf16 x-fragments; DEAD after pass_a.
#define OFF_CNT   3923968ul     // padded counters overlap xbuf (memset after pass_a)
#define OFF_WB    7135232ul
#define OFF_CM    8904704ul
#define OFF_BKT   19742976ul
#define WS_BIG    30580992ul
// ---- mid-ws layout (round-2, proven) ----
#define MOFF_KEYS  0ul
#define MOFF_N2MAX 401408ul
#define MOFF_C2    405504ul
#define MOFF_XN    516096ul
#define MOFF_XB    716800ul
#define MOFF_WB    3928064ul
#define MOFF_CM    5697536ul
#define WS_MID     16535552ul

__device__ __forceinline__ unsigned short rne_bf16(float f) {
    unsigned u = __float_as_uint(f);
    return (unsigned short)((u + 0x7FFFu + ((u >> 16) & 1u)) >> 16);
}
__device__ __forceinline__ float bf2f(unsigned short h) {
    return __uint_as_float(((unsigned)h) << 16);
}
__device__ __forceinline__ unsigned sortable(float s) {
    unsigned u = __float_as_uint(s);
    return (u & 0x80000000u) ? ~u : (u | 0x80000000u);
}

// ---------------- prep: vertices -> bf16 A-fragments + c2 + max|w~|^2 -----
__global__ void prep_v(const float* __restrict__ ve, short* __restrict__ wb,
                       float* __restrict__ c2buf, unsigned* __restrict__ n2max)
{
    int v = blockIdx.x * 256 + threadIdx.x;
    if (v >= VPAD) return;
    int c = v / CV, vl = v % CV;
    bf16x8 r0, r1, r2, r3;
#pragma unroll
    for (int k = 0; k < 8; ++k) { r2[k] = 0; r3[k] = 0; }
    if (v < V_TOT) {
        const float4* w4 = (const float4*)(ve + (size_t)v * DIMS);
        float w[16];
        *(float4*)&w[0] = w4[0]; *(float4*)&w[4]  = w4[1];
        *(float4*)&w[8] = w4[2]; *(float4*)&w[12] = w4[3];
        float c2 = 0.f;
#pragma unroll
        for (int k = 0; k < 16; ++k) c2 = fmaf(w[k], w[k], c2);
        c2buf[v] = c2;
        float n2 = 0.f;
#pragma unroll
        for (int k = 0; k < 16; ++k) {
            unsigned short h = rne_bf16(-2.f * w[k]);
            if (k < 8) r0[k] = (short)h; else r1[k - 8] = (short)h;
            float f = bf2f(h);
            n2 = fmaf(f, f, n2);
        }
        atomicMax(n2max, __float_as_uint(n2));
        unsigned short hi = rne_bf16(c2);
        unsigned short lo = rne_bf16(c2 - bf2f(hi));
        r2[0] = (short)hi; r2[1] = (short)lo;
    } else {
#pragma unroll
        for (int k = 0; k < 8; ++k) { r0[k] = 0; r1[k] = 0; }
        r2[0] = (short)rne_bf16(30000.f);   // padding: huge score, never wins
    }
    *(bf16x8*)(wb + (((size_t)c * 4 + 0) * CV + vl) * 8) = r0;
    *(bf16x8*)(wb + (((size_t)c * 4 + 1) * CV + vl) * 8) = r1;
    *(bf16x8*)(wb + (((size_t)c * 4 + 2) * CV + vl) * 8) = r2;
    *(bf16x8*)(wb + (((size_t)c * 4 + 3) * CV + vl) * 8) = r3;
}

// ------- prep: pixels -> bf16 B-fragments + |x~| (+ optional fp32 -2x) -----
__global__ void prep_x(const float* __restrict__ feats, short* __restrict__ xb,
                       float* __restrict__ xn, float* __restrict__ x2T)
{
    int p = blockIdx.x * 256 + threadIdx.x;
    int b = p / HW, hw = p - b * HW;
    const float* f = feats + (size_t)b * DIMS * HW + hw;
    bf16x8 r0, r1, r2, r3;
#pragma unroll
    for (int k = 0; k < 8; ++k) { r2[k] = 0; r3[k] = 0; }
    float n2 = 0.f;
    float xv[16];
#pragma unroll
    for (int k = 0; k < 16; ++k) {
        float fv = f[k * HW];
        xv[k] = -2.f * fv;
        unsigned short h = rne_bf16(fv);
        if (k < 8) r0[k] = (short)h; else r1[k - 8] = (short)h;
        float x = bf2f(h);
        n2 = fmaf(x, x, n2);
    }
    r2[0] = (short)0x3F80; r2[1] = (short)0x3F80;
    xn[p] = sqrtf(n2);
    if (x2T) {
        float4* o = (float4*)(x2T + (size_t)p * 16);
        o[0] = *(float4*)&xv[0];  o[1] = *(float4*)&xv[4];
        o[2] = *(float4*)&xv[8];  o[3] = *(float4*)&xv[12];
    }
    *(bf16x8*)(xb + ((size_t)0 * P_TOT + p) * 8) = r0;
    *(bf16x8*)(xb + ((size_t)1 * P_TOT + p) * 8) = r1;
    *(bf16x8*)(xb + ((size_t)2 * P_TOT + p) * 8) = r2;
    *(bf16x8*)(xb + ((size_t)3 * P_TOT + p) * 8) = r3;
}

// ---------------- pass A: MFMA approx, per-(pixel,chunk) min ---------------
__global__ __launch_bounds__(256)
void pass_a(const short* __restrict__ xb, const short* __restrict__ wb,
            float* __restrict__ chunkmin)
{
    __shared__ int4 wlds[4 * CV];
    const int c = blockIdx.y;
    const int4* wsrc = (const int4*)(wb + (size_t)c * 4 * CV * 8);
    for (int r = threadIdx.x; r < 4 * CV; r += 256) wlds[r] = wsrc[r];

    const int wid = threadIdx.x >> 6, lane = threadIdx.x & 63;
    const int q = lane >> 4, l15 = lane & 15;
    const int p0 = (blockIdx.x * 4 + wid) * PIXW;

    bf16x8 bfrag[TPW];
#pragma unroll
    for (int t = 0; t < TPW; ++t)
        bfrag[t] = *(const bf16x8*)(xb + ((size_t)q * P_TOT + p0 + t * 16 + l15) * 8);

    __syncthreads();

    f32x4 z = {0.f, 0.f, 0.f, 0.f};
    float run[TPW];
#pragma unroll
    for (int t = 0; t < TPW; ++t) run[t] = 3.0e38f;

    const short* wl = (const short*)wlds + (size_t)q * CV * 8;
#pragma unroll 2
    for (int s = 0; s < CV / 16; ++s) {
        bf16x8 a = *(const bf16x8*)(wl + (s * 16 + l15) * 8);
        f32x4 acc[TPW];
#pragma unroll
        for (int t = 0; t < TPW; ++t)
            acc[t] = __builtin_amdgcn_mfma_f32_16x16x32_bf16(a, bfrag[t], z, 0, 0, 0);
#pragma unroll
        for (int t = 0; t < TPW; ++t) {
            float m = fminf(fminf(acc[t][0], acc[t][1]), acc[t][2]);   // v_min3
            run[t] = fminf(fminf(run[t], acc[t][3]), m);               // v_min3
        }
    }
#pragma unroll
    for (int t = 0; t < TPW; ++t) {
        float v = run[t];
        v = fminf(v, __shfl_xor(v, 16, 64));
        v = fminf(v, __shfl_xor(v, 32, 64));
        if (lane < 16)
            chunkmin[(size_t)c * P_TOT + p0 + t * 16 + lane] = v;
    }
}

// ---- pass B1: thresholds + block-aggregated buckets (padded counters) -----
__global__ __launch_bounds__(256)
void pass_b1(const float* __restrict__ chunkmin, const float* __restrict__ xn,
             const unsigned* __restrict__ n2max,
             unsigned* __restrict__ cnt, unsigned* __restrict__ buckets)
{
    __shared__ unsigned hist[NCH];    // block-local candidate count per chunk
    __shared__ unsigned basech[NCH];  // global base for this block, per chunk
    __shared__ unsigned offch[NCH];   // running write offset within block

    const int tid  = threadIdx.x;
    const int p    = blockIdx.x * 256 + tid;
    const int lane = tid & 63;

    for (int i = tid; i < NCH; i += 256) { hist[i] = 0; offch[i] = 0; }
    __syncthreads();

    float cm[NCH];
    float gm = 3.0e38f;
#pragma unroll
    for (int c = 0; c < NCH; ++c) {
        cm[c] = chunkmin[(size_t)c * P_TOT + p];
        gm = fminf(gm, cm[c]);
    }
    float Wm = sqrtf(__uint_as_float(*n2max));
    float T = gm + 2.f * (0.004f * xn[p] * Wm + 1e-3f);

    // phase 1: LDS histogram, one LDS atomic per wave per chunk
#pragma unroll
    for (int c = 0; c < NCH; ++c) {
        unsigned long long m = __ballot(cm[c] <= T);
        if (m && lane == 0) atomicAdd(&hist[c], (unsigned)__popcll(m));
    }
    __syncthreads();

    // phase 2: ONE global atomic per (block, chunk); each counter on its own
    // 128B cacheline -> 54 parallel RMW chains (r6/r7 had 2 chains = 350us)
    for (int c = tid; c < NCH; c += 256) {
        unsigned h = hist[c];
        basech[c] = h ? atomicAdd(&cnt[(size_t)c * CNTSTRIDE], h) : 0u;
    }
    __syncthreads();

    // phase 3: wave-compacted writes at blockBase + LDS offset
#pragma unroll
    for (int c = 0; c < NCH; ++c) {
        bool want = (cm[c] <= T);
        unsigned long long m = __ballot(want);
        if (!m) continue;
        unsigned wbase = 0;
        int leader = __ffsll(m) - 1;
        if (lane == leader) wbase = atomicAdd(&offch[c], (unsigned)__popcll(m));
        wbase = __shfl(wbase, leader, 64);
        if (want) {
            unsigned pos = (unsigned)__popcll(m & ((1ull << lane) - 1ull));
            buckets[(size_t)c * P_TOT + basech[c] + wbase + pos] = (unsigned)p;
        }
    }
}

// ---------------- pass B2: wave-per-candidate exact fp32 refine ------------
__global__ __launch_bounds__(256)
void pass_b2(const unsigned* __restrict__ cnt, const unsigned* __restrict__ buckets,
             const float* __restrict__ ve, const float* __restrict__ c2buf,
             const float* __restrict__ x2T, unsigned long long* __restrict__ keys)
{
    __shared__ float wl[CV * 20];   // 40KB; row = 16 w + c2 + pad (80B stride)
    const int c = blockIdx.y;
    const int vbase = c * CV;
    const int rows = min(CV, V_TOT - vbase);
    for (int r = threadIdx.x; r < rows * 5; r += 256) {
        int v = r / 5, s = r % 5;
        if (s < 4)
            *(float4*)&wl[v * 20 + s * 4] =
                *(const float4*)(ve + (size_t)(vbase + v) * DIMS + s * 4);
        else
            wl[v * 20 + 16] = c2buf[vbase + v];
    }
    __syncthreads();

    const int wid = threadIdx.x >> 6, lane = threadIdx.x & 63;
    const unsigned n = cnt[(size_t)c * CNTSTRIDE];
    for (unsigned i = blockIdx.x * 4 + wid; i < n; i += B2BX * 4) {
        const unsigned p = buckets[(size_t)c * P_TOT + i];
        const float4* xq = (const float4*)(x2T + (size_t)p * 16);
        const float4 xa = xq[0], xb4 = xq[1], xc = xq[2], xd = xq[3];
        unsigned long long best = ~0ull;
#pragma unroll
        for (int k = 0; k < 8; ++k) {
            int v = k * 64 + lane;
            if (v < rows) {
                const float* row = &wl[v * 20];
                float4 a  = *(const float4*)(row);
                float4 b4 = *(const float4*)(row + 4);
                float4 cc = *(const float4*)(row + 8);
                float4 d4 = *(const float4*)(row + 12);
                float s = row[16];
                s = fmaf(xa.x,  a.x,  s); s = fmaf(xa.y,  a.y,  s);
                s = fmaf(xa.z,  a.z,  s); s = fmaf(xa.w,  a.w,  s);
                s = fmaf(xb4.x, b4.x, s); s = fmaf(xb4.y, b4.y, s);
                s = fmaf(xb4.z, b4.z, s); s = fmaf(xb4.w, b4.w, s);
                s = fmaf(xc.x,  cc.x, s); s = fmaf(xc.y,  cc.y, s);
                s = fmaf(xc.z,  cc.z, s); s = fmaf(xc.w,  cc.w, s);
                s = fmaf(xd.x,  d4.x, s); s = fmaf(xd.y,  d4.y, s);
                s = fmaf(xd.z,  d4.z, s); s = fmaf(xd.w,  d4.w, s);
                unsigned long long key =
                    ((unsigned long long)sortable(s) << 32) | (unsigned)(vbase + v);
                best = key < best ? key : best;
            }
        }
#pragma unroll
        for (int off = 32; off; off >>= 1) {
            unsigned long long o = __shfl_xor(best, off, 64);
            best = o < best ? o : best;
        }
        if (lane == 0) atomicMin(&keys[p], best);
    }
}

// ---------------- pass B serial (round-2 proven, mid-ws fallback) ----------
__global__ __launch_bounds__(256)
void pass_b(const float* __restrict__ chunkmin, const float* __restrict__ xn,
            const unsigned* __restrict__ n2max, const float* __restrict__ c2buf,
            const float* __restrict__ feats, const float* __restrict__ ve,
            unsigned long long* __restrict__ keys)
{
    __shared__ float cmins[NCH][64];
    __shared__ float Tsh[64];
    __shared__ float xlds[16][64];
    __shared__ unsigned long long candm[NCH];
    const int p0 = blockIdx.x * 64;
    const int tid = threadIdx.x;
    for (int i = tid; i < NCH * 64; i += 256) {
        int c = i >> 6, t = i & 63;
        cmins[c][t] = chunkmin[(size_t)c * P_TOT + p0 + t];
    }
    for (int i = tid; i < 16 * 64; i += 256) {
        int k = i >> 6, t = i & 63;
        int p = p0 + t, b = p / HW, hw = p - b * HW;
        xlds[k][t] = -2.f * feats[((size_t)b * DIMS + k) * HW + hw];
    }
    __syncthreads();
    if (tid < 64) {
        float gm = 3.0e38f;
        for (int c = 0; c < NCH; ++c) gm = fminf(gm, cmins[c][tid]);
        float Wm = sqrtf(__uint_as_float(*n2max));
        float mp = 0.004f * xn[p0 + tid] * Wm + 1e-3f;
        Tsh[tid] = gm + 2.f * mp;
    }
    __syncthreads();
    if (tid < 64) {
        for (int c = 0; c < NCH; ++c) {
            unsigned long long m = __ballot(cmins[c][tid] <= Tsh[tid]);
            if (tid == 0) candm[c] = m;
        }
    }
    __syncthreads();
    for (int c = 0; c < NCH; ++c) {
        unsigned long long m = candm[c];
        while (m) {
            int t = __ffsll((unsigned long long)m) - 1;
            m &= m - 1;
            unsigned long long best = ~0ull;
            int vend = min((c + 1) * CV, V_TOT);
            for (int v = c * CV + tid; v < vend; v += 256) {
                const float4* w4 = (const float4*)(ve + (size_t)v * DIMS);
                float4 a = w4[0], b4 = w4[1], cc = w4[2], d4 = w4[3];
                float s = c2buf[v];
                s = fmaf(xlds[0][t],  a.x,  s); s = fmaf(xlds[1][t],  a.y,  s);
                s = fmaf(xlds[2][t],  a.z,  s); s = fmaf(xlds[3][t],  a.w,  s);
                s = fmaf(xlds[4][t],  b4.x, s); s = fmaf(xlds[5][t],  b4.y, s);
                s = fmaf(xlds[6][t],  b4.z, s); s = fmaf(xlds[7][t],  b4.w, s);
                s = fmaf(xlds[8][t],  cc.x, s); s = fmaf(xlds[9][t],  cc.y, s);
                s = fmaf(xlds[10][t], cc.z, s); s = fmaf(xlds[11][t], cc.w, s);
                s = fmaf(xlds[12][t], d4.x, s); s = fmaf(xlds[13][t], d4.y, s);
                s = fmaf(xlds[14][t], d4.z, s); s = fmaf(xlds[15][t], d4.w, s);
                unsigned long long key =
                    ((unsigned long long)sortable(s) << 32) | (unsigned)v;
                best = (key < best) ? key : best;
            }
            for (int off = 32; off; off >>= 1) {
                unsigned long long o = __shfl_xor(best, off, 64);
                best = (o < best) ? o : best;
            }
            if ((tid & 63) == 0) atomicMin(&keys[p0 + t], best);
        }
    }
}

__global__ void cse_finalize(const unsigned long long* __restrict__ keys,
                             float* __restrict__ out)
{
    int p = blockIdx.x * 256 + threadIdx.x;
    if (p < P_TOT)
        out[FEAT_N + p] = (float)(unsigned)(keys[p] & 0xffffffffull);
}

// ---------------- fallback (round-1 proven VALU kernel) --------------------
__global__ __launch_bounds__(256, 2)
void cse_argmin(const float* __restrict__ feats, const float* __restrict__ ve,
                unsigned long long* __restrict__ keys)
{
    __shared__ float4 se4[VC * 4];
    __shared__ float  sh[VC];
    const int j = blockIdx.y, v0 = j * VC;
    const int cnt = min(VC, V_TOT - v0);
    for (int t = threadIdx.x; t < cnt; t += 256) {
        const float4* w4 = (const float4*)(ve + (size_t)(v0 + t) * DIMS);
        float4 a = w4[0], b = w4[1], c = w4[2], d = w4[3];
        float h = a.x*a.x + a.y*a.y + a.z*a.z + a.w*a.w
                + b.x*b.x + b.y*b.y + b.z*b.z + b.w*b.w
                + c.x*c.x + c.y*c.y + c.z*c.z + c.w*c.w
                + d.x*d.x + d.y*d.y + d.z*d.z + d.w*d.w;
        se4[t*4+0] = make_float4(-a.x,-a.y,-a.z,-a.w);
        se4[t*4+1] = make_float4(-b.x,-b.y,-b.z,-b.w);
        se4[t*4+2] = make_float4(-c.x,-c.y,-c.z,-c.w);
        se4[t*4+3] = make_float4(-d.x,-d.y,-d.z,-d.w);
        sh[t] = 0.5f * h;
    }
    __syncthreads();
    const int p0 = (blockIdx.x * 256 + threadIdx.x) * PPT;
    const int bb = p0 / HW, hw = p0 - bb * HW;
    const float* fb = feats + (size_t)bb * (DIMS * HW) + hw;
    float4 x[DIMS];
#pragma unroll
    for (int d = 0; d < DIMS; ++d) x[d] = *(const float4*)(fb + d * HW);
    float m0b = 3.4e38f, m1b = 3.4e38f, m2b = 3.4e38f, m3b = 3.4e38f;
    int i0 = 0, i1 = 0, i2 = 0, i3 = 0;
#pragma unroll 2
    for (int v = 0; v < cnt; ++v) {
        const float h = sh[v];
        float m0 = h, m1 = h, m2 = h, m3 = h;
#pragma unroll
        for (int k = 0; k < 4; ++k) {
            const float4 nw = se4[v*4 + k];
            const float4 xa = x[4*k+0], xb = x[4*k+1], xc = x[4*k+2], xd = x[4*k+3];
            m0 = fmaf(nw.x, xa.x, m0); m0 = fmaf(nw.y, xb.x, m0);
            m0 = fmaf(nw.z, xc.x, m0); m0 = fmaf(nw.w, xd.x, m0);
            m1 = fmaf(nw.x, xa.y, m1); m1 = fmaf(nw.y, xb.y, m1);
            m1 = fmaf(nw.z, xc.y, m1); m1 = fmaf(nw.w, xd.y, m1);
            m2 = fmaf(nw.x, xa.z, m2); m2 = fmaf(nw.y, xb.z, m2);
            m2 = fmaf(nw.z, xc.z, m2); m2 = fmaf(nw.w, xd.z, m2);
            m3 = fmaf(nw.x, xa.w, m3); m3 = fmaf(nw.y, xb.w, m3);
            m3 = fmaf(nw.z, xc.w, m3); m3 = fmaf(nw.w, xd.w, m3);
        }
        const int vg = v0 + v;
        bool c0 = m0 < m0b; m0b = c0 ? m0 : m0b; i0 = c0 ? vg : i0;
        bool c1 = m1 < m1b; m1b = c1 ? m1 : m1b; i1 = c1 ? vg : i1;
        bool c2 = m2 < m2b; m2b = c2 ? m2 : m2b; i2 = c2 ? vg : i2;
        bool c3 = m3 < m3b; m3b = c3 ? m3 : m3b; i3 = c3 ? vg : i3;
    }
    unsigned long long* kp = keys + p0;
    float mb[PPT] = { m0b, m1b, m2b, m3b };
    int   ib[PPT] = { i0, i1, i2, i3 };
#pragma unroll
    for (int p = 0; p < PPT; ++p) {
        unsigned long long key = ((unsigned long long)sortable(mb[p]) << 32) | (unsigned)ib[p];
        atomicMin(&kp[p], key);
    }
}

extern "C" void kernel_launch(void* const* d_in, const int* in_sizes, int n_in,
                              void* d_out, int out_size, void* d_ws, size_t ws_size,
                              hipStream_t stream)
{
    const float* feats = (const float*)d_in[0];
    const float* ve    = (const float*)d_in[1];
    float* out = (float*)d_out;
    char* ws = (char*)d_ws;

    hipMemcpyAsync(out, feats, (size_t)FEAT_N * sizeof(float),
                   hipMemcpyDeviceToDevice, stream);

    if (ws_size >= WS_BIG) {
        unsigned long long* keys = (unsigned long long*)(ws + OFF_KEYS);
        unsigned* n2max = (unsigned*)(ws + OFF_N2MAX);
        float* c2buf = (float*)(ws + OFF_C2);
        float* xnorm = (float*)(ws + OFF_XN);
        float* x2T   = (float*)(ws + OFF_X2T);
        short* xbuf  = (short*)(ws + OFF_XB);
        short* wbuf  = (short*)(ws + OFF_WB);
        float* cmin  = (float*)(ws + OFF_CM);
        unsigned* cnt = (unsigned*)(ws + OFF_CNT);   // overlaps xbuf (dead after pass_a)
        unsigned* bkt = (unsigned*)(ws + OFF_BKT);

        hipMemsetAsync(keys, 0xFF, (size_t)P_TOT * 8, stream);
        hipMemsetAsync(n2max, 0, 4, stream);

        prep_v<<<VPAD / 256, 256, 0, stream>>>(ve, wbuf, c2buf, n2max);
        prep_x<<<P_TOT / 256, 256, 0, stream>>>(feats, xbuf, xnorm, x2T);
        pass_a<<<dim3(P_TOT / (4 * PIXW), NCH), 256, 0, stream>>>(xbuf, wbuf, cmin);
        // xbuf is dead from here; zero the padded counters that alias it
        hipMemsetAsync(cnt, 0, (size_t)NCH * CNTSTRIDE * 4, stream);
        pass_b1<<<P_TOT / 256, 256, 0, stream>>>(cmin, xnorm, n2max, cnt, bkt);
        pass_b2<<<dim3(B2BX, NCH), 256, 0, stream>>>(cnt, bkt, ve, c2buf, x2T, keys);
        cse_finalize<<<(P_TOT + 255) / 256, 256, 0, stream>>>(keys, out);
    } else if (ws_size >= WS_MID) {
        unsigned long long* keys = (unsigned long long*)(ws + MOFF_KEYS);
        unsigned* n2max = (unsigned*)(ws + MOFF_N2MAX);
        float* c2buf = (float*)(ws + MOFF_C2);
        float* xnorm = (float*)(ws + MOFF_XN);
        short* xbuf  = (short*)(ws + MOFF_XB);
        short* wbuf  = (short*)(ws + MOFF_WB);
        float* cmin  = (float*)(ws + MOFF_CM);

        hipMemsetAsync(keys, 0xFF, (size_t)P_TOT * 8, stream);
        hipMemsetAsync(n2max, 0, 4, stream);

        prep_v<<<VPAD / 256, 256, 0, stream>>>(ve, wbuf, c2buf, n2max);
        prep_x<<<P_TOT / 256, 256, 0, stream>>>(feats, xbuf, xnorm, nullptr);
        pass_a<<<dim3(P_TOT / (4 * PIXW), NCH), 256, 0, stream>>>(xbuf, wbuf, cmin);
        pass_b<<<P_TOT / 64, 256, 0, stream>>>(cmin, xnorm, n2max, c2buf,
                                               feats, ve, keys);
        cse_finalize<<<(P_TOT + 255) / 256, 256, 0, stream>>>(keys, out);
    } else {
        unsigned long long* keys = (unsigned long long*)d_ws;
        hipMemsetAsync(d_ws, 0xFF, (size_t)P_TOT * 8, stream);
        cse_argmin<<<dim3(P_TOT / (256 * PPT), NV), 256, 0, stream>>>(feats, ve, keys);
        cse_finalize<<<(P_TOT + 255) / 256, 256, 0, stream>>>(keys, out);
    }
}

// Round 11
// 222.325 us; speedup vs baseline: 2.6527x; 1.0944x over previous
//
#include <hip/hip_runtime.h>
#include <stdint.h>

// CSENet: per-pixel argmin over 27554 vertex embeddings (16-dim, fp32).
// (A) bf16 MFMA approx scores s~ = c2 + (-2x~).w~ via mfma_f32_32x32x16_bf16
//     with K=16 == DIMS (dense; no wasted K slots) and c2 injected through the
//     C operand (free). min-reduce -> chunkmin[54][P] table.
//     HISTORY: r8 used 16x16x32 with c2 packed in K slots (18/32 useful) ->
//     98us at MfmaUtil 38%. K=16 dense + C-injection halves issued FLOPs.
// (B1) per-pixel per-chunk margin m_c = 0.004*|x~|*Wm_c + 1e-3 (Cauchy-Schwarz
//     bound on bf16 rounding, Wm_c = chunk max |w~|); candidate iff
//     cm[c]-m_c <= min_c'(cm[c']+m_c'). Block-aggregated buckets on 128B-padded
//     counters (r6/r7: same-cacheline atomic serialization = 350us; r8 fix).
// (B2) one wave per candidate (pixel,chunk): exact fp32 rescan from LDS
//     (80B row stride), packed u64 atomicMin(keys[p]) -- order-independent,
//     tie -> smaller index == np.argmin semantics.

#define DIMS   16
#define HW     12544
#define P_TOT  50176
#define V_TOT  27554
#define FEAT_N 802816

#define CV     512
#define NCH    54
#define VPAD   (NCH*CV)
#define PIXW   128
#define B2BX   32
#define CNTSTRIDE 32          // u32s per counter slot: 128B = own cacheline

// fallback (round-1) path
#define NV     64
#define VC     431
#define PPT    4

typedef __attribute__((ext_vector_type(8)))  short bf16x8;
typedef __attribute__((ext_vector_type(4)))  float f32x4;
typedef __attribute__((ext_vector_type(16))) float f32x16;

// ---- ws layout (bytes); WS_BIG branch confirmed taken r6-r8 ----
#define OFF_KEYS  0ul          // 50176*8
#define OFF_NMX   401408ul     // 54*128  (per-chunk max|w~|^2, padded lines)
#define OFF_CNT   408576ul     // 54*128  (bucket counters, padded lines)
#define OFF_C2    415744ul     // VPAD*4
#define OFF_XN    526336ul     // 50176*4
#define OFF_X2T   727040ul     // 50176*16*4
#define OFF_XB    3938304ul    // 2*50176*16  bf16 x-fragments (k-halves)
#define OFF_WB    5543936ul    // 54*2*512*16 bf16 w-fragments (k-halves)
#define OFF_CM    6428672ul    // 54*50176*4
#define OFF_BKT   17266688ul   // 54*50176*4
#define WS_BIG    30580992ul

__device__ __forceinline__ unsigned short rne_bf16(float f) {
    unsigned u = __float_as_uint(f);
    return (unsigned short)((u + 0x7FFFu + ((u >> 16) & 1u)) >> 16);
}
__device__ __forceinline__ float bf2f(unsigned short h) {
    return __uint_as_float(((unsigned)h) << 16);
}
__device__ __forceinline__ unsigned sortable(float s) {
    unsigned u = __float_as_uint(s);
    return (u & 0x80000000u) ? ~u : (u | 0x80000000u);
}

// ------- prep: vertices -> bf16 A-fragments + c2 + per-chunk max|w~|^2 -----
__global__ void prep_v(const float* __restrict__ ve, short* __restrict__ wb,
                       float* __restrict__ c2buf, unsigned* __restrict__ n2maxc)
{
    int v = blockIdx.x * 256 + threadIdx.x;
    if (v >= VPAD) return;
    int c = v / CV, vl = v % CV;
    int lane = threadIdx.x & 63;
    bf16x8 r0, r1;
    float c2 = 30000.f;   // padding rows: huge score, never wins a chunk-min
    float n2 = 0.f;
    if (v < V_TOT) {
        const float4* w4 = (const float4*)(ve + (size_t)v * DIMS);
        float w[16];
        *(float4*)&w[0] = w4[0]; *(float4*)&w[4]  = w4[1];
        *(float4*)&w[8] = w4[2]; *(float4*)&w[12] = w4[3];
        c2 = 0.f;
#pragma unroll
        for (int k = 0; k < 16; ++k) c2 = fmaf(w[k], w[k], c2);
#pragma unroll
        for (int k = 0; k < 16; ++k) {
            unsigned short h = rne_bf16(-2.f * w[k]);
            if (k < 8) r0[k] = (short)h; else r1[k - 8] = (short)h;
            float f = bf2f(h);
            n2 = fmaf(f, f, n2);
        }
    } else {
#pragma unroll
        for (int k = 0; k < 8; ++k) { r0[k] = 0; r1[k] = 0; }
    }
    c2buf[v] = c2;
    // wave-reduce max(n2): CV%64==0 -> whole wave in one chunk; 1 atomic/wave
#pragma unroll
    for (int off = 32; off; off >>= 1)
        n2 = fmaxf(n2, __shfl_xor(n2, off, 64));
    if (lane == 0)
        atomicMax(&n2maxc[(size_t)c * CNTSTRIDE], __float_as_uint(n2));
    *(bf16x8*)(wb + (((size_t)c * 2 + 0) * CV + vl) * 8) = r0;
    *(bf16x8*)(wb + (((size_t)c * 2 + 1) * CV + vl) * 8) = r1;
}

// ------- prep: pixels -> bf16 B-fragments (k-halves) + |x~| + fp32 -2x -----
__global__ void prep_x(const float* __restrict__ feats, short* __restrict__ xb,
                       float* __restrict__ xn, float* __restrict__ x2T)
{
    int p = blockIdx.x * 256 + threadIdx.x;
    int b = p / HW, hw = p - b * HW;
    const float* f = feats + (size_t)b * DIMS * HW + hw;
    bf16x8 r0, r1;
    float n2 = 0.f;
    float xv[16];
#pragma unroll
    for (int k = 0; k < 16; ++k) {
        float fv = f[k * HW];
        xv[k] = -2.f * fv;
        unsigned short h = rne_bf16(fv);
        if (k < 8) r0[k] = (short)h; else r1[k - 8] = (short)h;
        float x = bf2f(h);
        n2 = fmaf(x, x, n2);
    }
    xn[p] = sqrtf(n2);
    float4* o = (float4*)(x2T + (size_t)p * 16);
    o[0] = *(float4*)&xv[0];  o[1] = *(float4*)&xv[4];
    o[2] = *(float4*)&xv[8];  o[3] = *(float4*)&xv[12];
    *(bf16x8*)(xb + ((size_t)0 * P_TOT + p) * 8) = r0;
    *(bf16x8*)(xb + ((size_t)1 * P_TOT + p) * 8) = r1;
}

// -------- pass A: 32x32x16 MFMA (c2 in C operand), per-(pixel,chunk) min ---
__global__ __launch_bounds__(256)
void pass_a(const short* __restrict__ xb, const short* __restrict__ wb,
            const float* __restrict__ c2buf, float* __restrict__ chunkmin)
{
    __shared__ short wlds[2 * CV * 8];   // 16KB: [khalf][CV][8]
    __shared__ float c2lds[CV];          // 2KB

    const int c = blockIdx.y;
    const int4* wsrc = (const int4*)(wb + (size_t)c * 2 * CV * 8);
    int4* wdst = (int4*)wlds;
    for (int r = threadIdx.x; r < 2 * CV; r += 256) wdst[r] = wsrc[r];
    const float4* csrc = (const float4*)(c2buf + (size_t)c * CV);
    float4* cdst = (float4*)c2lds;
    for (int r = threadIdx.x; r < CV / 4; r += 256) cdst[r] = csrc[r];

    const int wid = threadIdx.x >> 6, lane = threadIdx.x & 63;
    const int col = lane & 31, hi = lane >> 5;
    const int p0 = (blockIdx.x * 4 + wid) * PIXW;

    bf16x8 bfrag[4];
#pragma unroll
    for (int t = 0; t < 4; ++t)
        bfrag[t] = *(const bf16x8*)(xb + ((size_t)hi * P_TOT + p0 + t * 32 + col) * 8);

    __syncthreads();

    float run[4] = {3.0e38f, 3.0e38f, 3.0e38f, 3.0e38f};
    const short* wl = wlds + (size_t)hi * CV * 8;

#pragma unroll 2
    for (int s = 0; s < CV / 32; ++s) {
        bf16x8 a = *(const bf16x8*)(wl + (s * 32 + col) * 8);   // ds_read_b128
        union { f32x16 v; f32x4 q[4]; } c2f;   // C-frag: row=(r&3)+8*(r>>2)+4*hi
#pragma unroll
        for (int g = 0; g < 4; ++g)
            c2f.q[g] = *(const f32x4*)&c2lds[s * 32 + 4 * hi + 8 * g];
#pragma unroll
        for (int t = 0; t < 4; ++t) {
            f32x16 acc = __builtin_amdgcn_mfma_f32_32x32x16_bf16(
                a, bfrag[t], c2f.v, 0, 0, 0);
            float m0 = fminf(fminf(acc[0],  acc[1]),  acc[2]);   // v_min3 tree
            float m1 = fminf(fminf(acc[3],  acc[4]),  acc[5]);
            float m2 = fminf(fminf(acc[6],  acc[7]),  acc[8]);
            float m3 = fminf(fminf(acc[9],  acc[10]), acc[11]);
            float m4 = fminf(fminf(acc[12], acc[13]), acc[14]);
            float mm = fminf(fminf(m0, m1), m2);
            mm = fminf(fminf(mm, m3), m4);
            mm = fminf(mm, acc[15]);
            mm = fminf(mm, __shfl_xor(mm, 32, 64));   // rows split across hi
            run[t] = fminf(run[t], mm);
        }
    }
#pragma unroll
    for (int t = 0; t < 4; ++t)
        if (lane < 32)
            chunkmin[(size_t)c * P_TOT + p0 + t * 32 + lane] = run[t];
}

// -- pass B1: per-chunk margins + block-aggregated buckets (padded counters) -
__global__ __launch_bounds__(256)
void pass_b1(const float* __restrict__ chunkmin, const float* __restrict__ xn,
             const unsigned* __restrict__ n2maxc,
             unsigned* __restrict__ cnt, unsigned* __restrict__ buckets)
{
    __shared__ float    wms[NCH];     // sqrt of per-chunk max |w~|^2
    __shared__ unsigned hist[NCH];
    __shared__ unsigned basech[NCH];
    __shared__ unsigned offch[NCH];

    const int tid  = threadIdx.x;
    const int p    = blockIdx.x * 256 + tid;
    const int lane = tid & 63;

    for (int i = tid; i < NCH; i += 256) {
        wms[i] = sqrtf(__uint_as_float(n2maxc[(size_t)i * CNTSTRIDE]));
        hist[i] = 0; offch[i] = 0;
    }
    __syncthreads();

    const float kx = 0.004f * xn[p];
    float cm[NCH];
    float gmp = 3.0e38f;            // min over chunks of (cm + m_c)
#pragma unroll
    for (int c = 0; c < NCH; ++c) {
        cm[c] = chunkmin[(size_t)c * P_TOT + p];
        gmp = fminf(gmp, cm[c] + fmaf(kx, wms[c], 1e-3f));
    }

    // phase 1: LDS histogram (one LDS atomic per wave per chunk)
#pragma unroll
    for (int c = 0; c < NCH; ++c) {
        bool want = (cm[c] - fmaf(kx, wms[c], 1e-3f)) <= gmp;
        unsigned long long m = __ballot(want);
        if (m && lane == 0) atomicAdd(&hist[c], (unsigned)__popcll(m));
    }
    __syncthreads();

    // phase 2: one global atomic per (block, chunk); padded counter lines
    for (int c = tid; c < NCH; c += 256) {
        unsigned h = hist[c];
        basech[c] = h ? atomicAdd(&cnt[(size_t)c * CNTSTRIDE], h) : 0u;
    }
    __syncthreads();

    // phase 3: wave-compacted bucket writes at blockBase + LDS offset
#pragma unroll
    for (int c = 0; c < NCH; ++c) {
        bool want = (cm[c] - fmaf(kx, wms[c], 1e-3f)) <= gmp;
        unsigned long long m = __ballot(want);
        if (!m) continue;
        unsigned wbase = 0;
        int leader = __ffsll(m) - 1;
        if (lane == leader) wbase = atomicAdd(&offch[c], (unsigned)__popcll(m));
        wbase = __shfl(wbase, leader, 64);
        if (want) {
            unsigned pos = (unsigned)__popcll(m & ((1ull << lane) - 1ull));
            buckets[(size_t)c * P_TOT + basech[c] + wbase + pos] = (unsigned)p;
        }
    }
}

// ---------------- pass B2: wave-per-candidate exact fp32 refine ------------
__global__ __launch_bounds__(256)
void pass_b2(const unsigned* __restrict__ cnt, const unsigned* __restrict__ buckets,
             const float* __restrict__ ve, const float* __restrict__ c2buf,
             const float* __restrict__ x2T, unsigned long long* __restrict__ keys)
{
    __shared__ float wl[CV * 20];   // 40KB; row = 16 w + c2 + pad (80B stride)
    const int c = blockIdx.y;
    const int vbase = c * CV;
    const int rows = min(CV, V_TOT - vbase);
    for (int r = threadIdx.x; r < rows * 5; r += 256) {
        int v = r / 5, s = r % 5;
        if (s < 4)
            *(float4*)&wl[v * 20 + s * 4] =
                *(const float4*)(ve + (size_t)(vbase + v) * DIMS + s * 4);
        else
            wl[v * 20 + 16] = c2buf[vbase + v];
    }
    __syncthreads();

    const int wid = threadIdx.x >> 6, lane = threadIdx.x & 63;
    const unsigned n = cnt[(size_t)c * CNTSTRIDE];
    for (unsigned i = blockIdx.x * 4 + wid; i < n; i += B2BX * 4) {
        const unsigned p = buckets[(size_t)c * P_TOT + i];
        const float4* xq = (const float4*)(x2T + (size_t)p * 16);
        const float4 xa = xq[0], xb4 = xq[1], xc = xq[2], xd = xq[3];
        unsigned long long best = ~0ull;
#pragma unroll
        for (int k = 0; k < 8; ++k) {
            int v = k * 64 + lane;
            if (v < rows) {
                const float* row = &wl[v * 20];
                float4 a  = *(const float4*)(row);
                float4 b4 = *(const float4*)(row + 4);
                float4 cc = *(const float4*)(row + 8);
                float4 d4 = *(const float4*)(row + 12);
                float s = row[16];
                s = fmaf(xa.x,  a.x,  s); s = fmaf(xa.y,  a.y,  s);
                s = fmaf(xa.z,  a.z,  s); s = fmaf(xa.w,  a.w,  s);
                s = fmaf(xb4.x, b4.x, s); s = fmaf(xb4.y, b4.y, s);
                s = fmaf(xb4.z, b4.z, s); s = fmaf(xb4.w, b4.w, s);
                s = fmaf(xc.x,  cc.x, s); s = fmaf(xc.y,  cc.y, s);
                s = fmaf(xc.z,  cc.z, s); s = fmaf(xc.w,  cc.w, s);
                s = fmaf(xd.x,  d4.x, s); s = fmaf(xd.y,  d4.y, s);
                s = fmaf(xd.z,  d4.z, s); s = fmaf(xd.w,  d4.w, s);
                unsigned long long key =
                    ((unsigned long long)sortable(s) << 32) | (unsigned)(vbase + v);
                best = key < best ? key : best;
            }
        }
#pragma unroll
        for (int off = 32; off; off >>= 1) {
            unsigned long long o = __shfl_xor(best, off, 64);
            best = o < best ? o : best;
        }
        if (lane == 0) atomicMin(&keys[p], best);
    }
}

__global__ void cse_finalize(const unsigned long long* __restrict__ keys,
                             float* __restrict__ out)
{
    int p = blockIdx.x * 256 + threadIdx.x;
    if (p < P_TOT)
        out[FEAT_N + p] = (float)(unsigned)(keys[p] & 0xffffffffull);
}

// ---------------- fallback (round-1 proven VALU kernel) --------------------
__global__ __launch_bounds__(256, 2)
void cse_argmin(const float* __restrict__ feats, const float* __restrict__ ve,
                unsigned long long* __restrict__ keys)
{
    __shared__ float4 se4[VC * 4];
    __shared__ float  sh[VC];
    const int j = blockIdx.y, v0 = j * VC;
    const int cnt = min(VC, V_TOT - v0);
    for (int t = threadIdx.x; t < cnt; t += 256) {
        const float4* w4 = (const float4*)(ve + (size_t)(v0 + t) * DIMS);
        float4 a = w4[0], b = w4[1], c = w4[2], d = w4[3];
        float h = a.x*a.x + a.y*a.y + a.z*a.z + a.w*a.w
                + b.x*b.x + b.y*b.y + b.z*b.z + b.w*b.w
                + c.x*c.x + c.y*c.y + c.z*c.z + c.w*c.w
                + d.x*d.x + d.y*d.y + d.z*d.z + d.w*d.w;
        se4[t*4+0] = make_float4(-a.x,-a.y,-a.z,-a.w);
        se4[t*4+1] = make_float4(-b.x,-b.y,-b.z,-b.w);
        se4[t*4+2] = make_float4(-c.x,-c.y,-c.z,-c.w);
        se4[t*4+3] = make_float4(-d.x,-d.y,-d.z,-d.w);
        sh[t] = 0.5f * h;
    }
    __syncthreads();
    const int p0 = (blockIdx.x * 256 + threadIdx.x) * PPT;
    const int bb = p0 / HW, hw = p0 - bb * HW;
    const float* fb = feats + (size_t)bb * (DIMS * HW) + hw;
    float4 x[DIMS];
#pragma unroll
    for (int d = 0; d < DIMS; ++d) x[d] = *(const float4*)(fb + d * HW);
    float m0b = 3.4e38f, m1b = 3.4e38f, m2b = 3.4e38f, m3b = 3.4e38f;
    int i0 = 0, i1 = 0, i2 = 0, i3 = 0;
#pragma unroll 2
    for (int v = 0; v < cnt; ++v) {
        const float h = sh[v];
        float m0 = h, m1 = h, m2 = h, m3 = h;
#pragma unroll
        for (int k = 0; k < 4; ++k) {
            const float4 nw = se4[v*4 + k];
            const float4 xa = x[4*k+0], xb = x[4*k+1], xc = x[4*k+2], xd = x[4*k+3];
            m0 = fmaf(nw.x, xa.x, m0); m0 = fmaf(nw.y, xb.x, m0);
            m0 = fmaf(nw.z, xc.x, m0); m0 = fmaf(nw.w, xd.x, m0);
            m1 = fmaf(nw.x, xa.y, m1); m1 = fmaf(nw.y, xb.y, m1);
            m1 = fmaf(nw.z, xc.y, m1); m1 = fmaf(nw.w, xd.y, m1);
            m2 = fmaf(nw.x, xa.z, m2); m2 = fmaf(nw.y, xb.z, m2);
            m2 = fmaf(nw.z, xc.z, m2); m2 = fmaf(nw.w, xd.z, m2);
            m3 = fmaf(nw.x, xa.w, m3); m3 = fmaf(nw.y, xb.w, m3);
            m3 = fmaf(nw.z, xc.w, m3); m3 = fmaf(nw.w, xd.w, m3);
        }
        const int vg = v0 + v;
        bool c0 = m0 < m0b; m0b = c0 ? m0 : m0b; i0 = c0 ? vg : i0;
        bool c1 = m1 < m1b; m1b = c1 ? m1 : m1b; i1 = c1 ? vg : i1;
        bool c2 = m2 < m2b; m2b = c2 ? m2 : m2b; i2 = c2 ? vg : i2;
        bool c3 = m3 < m3b; m3b = c3 ? m3 : m3b; i3 = c3 ? vg : i3;
    }
    unsigned long long* kp = keys + p0;
    float mb[PPT] = { m0b, m1b, m2b, m3b };
    int   ib[PPT] = { i0, i1, i2, i3 };
#pragma unroll
    for (int p = 0; p < PPT; ++p) {
        unsigned long long key = ((unsigned long long)sortable(mb[p]) << 32) | (unsigned)ib[p];
        atomicMin(&kp[p], key);
    }
}

extern "C" void kernel_launch(void* const* d_in, const int* in_sizes, int n_in,
                              void* d_out, int out_size, void* d_ws, size_t ws_size,
                              hipStream_t stream)
{
    const float* feats = (const float*)d_in[0];
    const float* ve    = (const float*)d_in[1];
    float* out = (float*)d_out;
    char* ws = (char*)d_ws;

    hipMemcpyAsync(out, feats, (size_t)FEAT_N * sizeof(float),
                   hipMemcpyDeviceToDevice, stream);

    if (ws_size >= WS_BIG) {
        unsigned long long* keys = (unsigned long long*)(ws + OFF_KEYS);
        unsigned* n2maxc = (unsigned*)(ws + OFF_NMX);
        unsigned* cnt    = (unsigned*)(ws + OFF_CNT);
        float* c2buf = (float*)(ws + OFF_C2);
        float* xnorm = (float*)(ws + OFF_XN);
        float* x2T   = (float*)(ws + OFF_X2T);
        short* xbuf  = (short*)(ws + OFF_XB);
        short* wbuf  = (short*)(ws + OFF_WB);
        float* cmin  = (float*)(ws + OFF_CM);
        unsigned* bkt = (unsigned*)(ws + OFF_BKT);

        hipMemsetAsync(keys, 0xFF, (size_t)P_TOT * 8, stream);
        hipMemsetAsync(n2maxc, 0, (size_t)NCH * CNTSTRIDE * 4, stream);
        hipMemsetAsync(cnt, 0, (size_t)NCH * CNTSTRIDE * 4, stream);

        prep_v<<<VPAD / 256, 256, 0, stream>>>(ve, wbuf, c2buf, n2maxc);
        prep_x<<<P_TOT / 256, 256, 0, stream>>>(feats, xbuf, xnorm, x2T);
        pass_a<<<dim3(P_TOT / (4 * PIXW), NCH), 256, 0, stream>>>(xbuf, wbuf,
                                                                  c2buf, cmin);
        pass_b1<<<P_TOT / 256, 256, 0, stream>>>(cmin, xnorm, n2maxc, cnt, bkt);
        pass_b2<<<dim3(B2BX, NCH), 256, 0, stream>>>(cnt, bkt, ve, c2buf, x2T, keys);
        cse_finalize<<<(P_TOT + 255) / 256, 256, 0, stream>>>(keys, out);
    } else {
        unsigned long long* keys = (unsigned long long*)d_ws;
        hipMemsetAsync(d_ws, 0xFF, (size_t)P_TOT * 8, stream);
        cse_argmin<<<dim3(P_TOT / (256 * PPT), NV), 256, 0, stream>>>(feats, ve, keys);
        cse_finalize<<<(P_TOT + 255) / 256, 256, 0, stream>>>(keys, out);
    }
}